// Round 1
// baseline (14079.254 us; speedup 1.0000x reference)
//
#include <hip/hip_runtime.h>

// Transposed conv, stride 2, 4x4 kernel, ext pad 2.
// x: (32,256,32,32) f32, W: (128,256,4,4) OIHW f32, b: (128,) f32
// out: (32,128,64,64) f32
//
// Parity decomposition: for output (i,j), pi=i&1, pj=j&1, a=i>>1, b=j>>1:
//   y[n,o,i,j] = bias[o] + sum_c sum_{du,dv in {0,1}}
//                W[o,c,pi+2du,pj+2dv] * x[n,c,a+pi-1+du, b+pj-1+dv]   (OOB -> 0)

#define CIN   256
#define COUT  128
#define HIN   32
#define WIN   32
#define HOUT  64
#define WOUT  64
#define CC    8     // c-chunk staged per iteration

// Block: 256 threads. tid -> tx = tid&15 (pj = tx&1, bq = tx>>1 in [0,8)),
//                            ty = tid>>4 in [0,16) (o = ty*8 + r, r in [0,8))
// Thread computes 2 i's (same parity) x 4 j's (b = bq*4+q) x 8 o's = 64 outputs.
// Grid: (32, 32): bx -> pi = bx&1, a0 = (bx>>1)*2 ; by = n.

__global__ __launch_bounds__(256, 4) void tconv_kernel(
    const float* __restrict__ x, const float* __restrict__ W,
    const float* __restrict__ bias, float* __restrict__ out)
{
    // Wsh: per (cc, pj, o): 4 floats [du][dv], b128-readable.
    // 16B-unit index idx16 = (cc*2+pj)*128 + o, XOR-swizzled by ((o>>3)&3)
    // to break the o-stride-8 bank aliasing on reads.
    __shared__ float Wsh[CC * 2 * COUT * 4];   // 32 KB
    // Xsh: per (cc, row in [0,3)): 36 floats, vv = v+1 (v in [-1,34))
    __shared__ float Xsh[CC * 3 * 36];         // 3.4 KB

    const int tid = threadIdx.x;
    const int tx  = tid & 15;
    const int ty  = tid >> 4;
    const int pj  = tx & 1;
    const int bq  = tx >> 1;

    const int n   = blockIdx.y;
    const int bx  = blockIdx.x;
    const int pi  = bx & 1;
    const int a0  = (bx >> 1) * 2;     // block covers a in {a0, a0+1}
    const int us  = a0 + pi - 1;       // lowest input row needed

    float acc[2][4][8];
    #pragma unroll
    for (int i2 = 0; i2 < 2; ++i2)
        #pragma unroll
        for (int q = 0; q < 4; ++q)
            #pragma unroll
            for (int r = 0; r < 8; ++r)
                acc[i2][q][r] = 0.f;

    const int vbase = bq * 4 + pj;     // Xsh column base for this thread

    for (int ch = 0; ch < CIN / CC; ++ch) {
        const int c0 = ch * CC;
        __syncthreads();   // previous chunk's compute done before restage

        // ---- stage W: 2048 triples (cc,du,o), each one float4 global load ----
        #pragma unroll
        for (int it = 0; it < 8; ++it) {
            int s  = it * 256 + tid;        // [0, 2048)
            int cc = s & 7;
            int du = (s >> 3) & 1;
            int o  = s >> 4;                // [0, 128)
            int c  = c0 + cc;
            const float4 w4 = *(const float4*)(W + (size_t)(((o * CIN + c) * 4 + (pi + 2 * du)) * 4));
            // kw = pj + 2*dv:  w4.x=(pj0,dv0) w4.y=(pj1,dv0) w4.z=(pj0,dv1) w4.w=(pj1,dv1)
            int i16_0 = ((cc * 2 + 0) * COUT + o) ^ ((o >> 3) & 3);
            int i16_1 = ((cc * 2 + 1) * COUT + o) ^ ((o >> 3) & 3);
            *(float2*)&Wsh[i16_0 * 4 + du * 2] = make_float2(w4.x, w4.z);
            *(float2*)&Wsh[i16_1 * 4 + du * 2] = make_float2(w4.y, w4.w);
        }

        // ---- stage X: rows us..us+2 for this c-chunk, zero-padded ----
        for (int idx = tid; idx < CC * 3 * 36; idx += 256) {
            int vv  = idx % 36;
            int pr  = idx / 36;         // cc*3 + row
            int row = pr % 3;
            int cc  = pr / 3;
            int u   = us + row;
            int v   = vv - 1;
            float val = 0.f;
            if ((unsigned)u < (unsigned)HIN && (unsigned)v < (unsigned)WIN)
                val = x[(size_t)(((n * CIN + (c0 + cc)) * HIN + u) * WIN + v)];
            Xsh[pr * 36 + vv] = val;
        }

        __syncthreads();

        // ---- compute ----
        #pragma unroll
        for (int cc = 0; cc < CC; ++cc) {
            float xr[3][5];
            #pragma unroll
            for (int row = 0; row < 3; ++row)
                #pragma unroll
                for (int k = 0; k < 5; ++k)
                    xr[row][k] = Xsh[(cc * 3 + row) * 36 + vbase + k];

            #pragma unroll
            for (int r = 0; r < 8; ++r) {
                int o = ty * 8 + r;
                int idx16 = ((cc * 2 + pj) * COUT + o) ^ ((o >> 3) & 3);
                float4 w = *(const float4*)&Wsh[idx16 * 4];
                #pragma unroll
                for (int i2 = 0; i2 < 2; ++i2)
                    #pragma unroll
                    for (int q = 0; q < 4; ++q)
                        acc[i2][q][r] += w.x * xr[i2][q]
                                       + w.y * xr[i2][q + 1]
                                       + w.z * xr[i2 + 1][q]
                                       + w.w * xr[i2 + 1][q + 1];
            }
        }
    }

    // ---- epilogue: bias + store ----
    #pragma unroll
    for (int r = 0; r < 8; ++r) {
        int o = ty * 8 + r;
        float bv = bias[o];
        #pragma unroll
        for (int i2 = 0; i2 < 2; ++i2) {
            int i = 2 * (a0 + i2) + pi;
            #pragma unroll
            for (int q = 0; q < 4; ++q) {
                int j = (bq * 4 + q) * 2 + pj;
                out[(size_t)(((n * COUT + o) * HOUT + i) * WOUT + j)] = acc[i2][q][r] + bv;
            }
        }
    }
}

extern "C" void kernel_launch(void* const* d_in, const int* in_sizes, int n_in,
                              void* d_out, int out_size, void* d_ws, size_t ws_size,
                              hipStream_t stream) {
    const float* x    = (const float*)d_in[0];
    const float* W    = (const float*)d_in[1];
    const float* bias = (const float*)d_in[2];
    float* out        = (float*)d_out;

    dim3 grid(32, 32);   // (i-pairs x parity, n)
    tconv_kernel<<<grid, 256, 0, stream>>>(x, W, bias, out);
}

// Round 2
// 84.809 us; speedup vs baseline: 166.0113x; 166.0113x over previous
//
#include <hip/hip_runtime.h>

// Transposed conv (stride 2, 4x4 kernel, ext pad 2) as bf16 MFMA implicit GEMM.
// x: (32,256,32,32) f32, W: (128,256,4,4) OIHW f32, b: (128,), out: (32,128,64,64) f32
//
// Parity decomposition (verified in round 1): pi=i&1, pj=j&1, a=i>>1, b=j>>1:
//   y[n,o,i,j] = bias[o] + sum_{c,du,dv} W[o,c,pi+2du,pj+2dv] * x[n,c,a+pi-1+du,b+pj-1+dv]
// GEMM: A = W' (M=128 o, K=1024=(c,du,dv)), B = X' (K x N pixels), per (pi,pj).
// K-chunk of 32 = 4 (du,dv) "sub" planes x 8 consecutive c  ->  k = sub*8 + c_off,
// matching the mfma_f32_16x16x32_bf16 fragment layout (lane l: k = 8*(l>>4)+e).

typedef float  f32x4  __attribute__((ext_vector_type(4)));
typedef short  short8 __attribute__((ext_vector_type(8)));
typedef unsigned short ushort4v __attribute__((ext_vector_type(4)));

__device__ __forceinline__ unsigned short f2bf(float f) {
    unsigned u = __builtin_bit_cast(unsigned, f);
    u += 0x7fffu + ((u >> 16) & 1u);          // RNE (inputs are finite)
    return (unsigned short)(u >> 16);
}

// Prepass: Wp[pi][pj][sub=2du+dv][o][c] = bf16(W[o][c][pi+2du][pj+2dv]); 1 MB.
__global__ __launch_bounds__(256) void prepack_w(const float* __restrict__ W,
                                                 unsigned short* __restrict__ Wp) {
    int t = blockIdx.x * 256 + threadIdx.x;   // [0, 32768) = (o,c)
    int o = t >> 8, c = t & 255;
    const float4* src = (const float4*)(W + (size_t)(o * 256 + c) * 16);
    float4 q0 = src[0], q1 = src[1], q2 = src[2], q3 = src[3];
    float rows[4][4] = {{q0.x,q0.y,q0.z,q0.w},{q1.x,q1.y,q1.z,q1.w},
                        {q2.x,q2.y,q2.z,q2.w},{q3.x,q3.y,q3.z,q3.w}};
    #pragma unroll
    for (int pi = 0; pi < 2; ++pi)
    #pragma unroll
    for (int pj = 0; pj < 2; ++pj)
    #pragma unroll
    for (int du = 0; du < 2; ++du)
    #pragma unroll
    for (int dv = 0; dv < 2; ++dv)
        Wp[((((pi*2+pj)*4 + du*2+dv)*128 + o)*256) + c] = f2bf(rows[pi+2*du][pj+2*dv]);
}

// Block: 512 thr = 8 waves. bid -> (pi, aq in [0,4), n). Tile: 128 o x [8 arows x 32 b x 2 pj].
// Wave w: pj = w>>2, q = w&3 -> 4 N-subtiles (arow = q*2+(jj>>1), bhalf = jj&1).
template<bool PRE>
__global__ __launch_bounds__(512, 2) void tconv_mfma(
    const float* __restrict__ x, const float* __restrict__ W,
    const unsigned short* __restrict__ Wp, const float* __restrict__ bias,
    float* __restrict__ out)
{
    // xsh: [buf][rr(9)][cw(34)][c(8)] bf16 ; value = x[n, c0+c, u0+rr, cw-1] (OOB=0)
    __shared__ __align__(16) unsigned short xsh[2][9 * 34 * 8];
    // wsh: [buf][pj(2)][sub(4)][o(128)][c(8)] bf16
    __shared__ __align__(16) unsigned short wsh[2][2 * 4 * 128 * 8];

    const int tid = threadIdx.x;
    const int bid = blockIdx.x;
    const int pi  = bid & 1;
    const int aq  = (bid >> 1) & 3;
    const int n   = bid >> 3;
    const int a0  = aq * 8;
    const int u0  = a0 + pi - 1;

    const int l   = tid & 63;
    const int w   = tid >> 6;
    const int pjw = w >> 2;
    const int q   = w & 3;
    const int lg  = l >> 4;      // k-group / sub
    const int ln  = l & 15;      // row (A) / col (B)

    const int sv = tid & 31;     // x-stage: v
    const int sg = tid >> 5;     // x-stage: pair group [0,16)

    f32x4 acc[8][4];
    #pragma unroll
    for (int i = 0; i < 8; ++i)
        #pragma unroll
        for (int jj = 0; jj < 4; ++jj)
            acc[i][jj] = (f32x4){0.f, 0.f, 0.f, 0.f};

    float    xv[5];
    ushort4v wv[4];
    float4   wa[2], wb[2];

    auto stage_load = [&](int ch) {
        const int c0 = ch * 8;
        #pragma unroll
        for (int s = 0; s < 5; ++s) {
            int p = sg * 5 + s;                       // 72 (c,rr) pairs
            if (p < 72) {
                int c = p & 7, rr = p >> 3;
                int u = u0 + rr;
                xv[s] = ((unsigned)u < 32u)
                      ? x[((n*256 + c0 + c)*32 + u)*32 + sv] : 0.f;
            }
        }
        if (PRE) {
            #pragma unroll
            for (int k = 0; k < 4; ++k) {
                int uu = tid + k * 512;               // [0,2048) = 8192 bf16 / 4
                int chalf = uu & 1, o = (uu >> 1) & 127;
                int sub = (uu >> 8) & 3, pjq = (uu >> 10) & 1;
                wv[k] = *(const ushort4v*)&Wp[(((pi*2 + pjq)*4 + sub)*128 + o)*256
                                              + c0 + chalf*4];
            }
        } else {
            #pragma unroll
            for (int k = 0; k < 2; ++k) {
                int pr = tid + k * 512;               // 1024 (o,c) pairs
                int o = pr >> 3, c = pr & 7;
                const float* base = W + ((o*256 + c0 + c) << 4) + pi*4;
                wa[k] = *(const float4*)base;         // kh = pi,   kw 0..3
                wb[k] = *(const float4*)(base + 8);   // kh = pi+2, kw 0..3
            }
        }
    };

    auto stage_write = [&](int buf) {
        #pragma unroll
        for (int s = 0; s < 5; ++s) {
            int p = sg * 5 + s;
            if (p < 72) {
                int c = p & 7, rr = p >> 3;
                xsh[buf][(rr*34 + sv + 1)*8 + c] = f2bf(xv[s]);
            }
        }
        if (tid < 144) {                              // halo cols cw=0,33 -> 0
            int pr = tid >> 1;
            int rr = pr >> 3, c = pr & 7;
            int cw = (tid & 1) * 33;
            xsh[buf][(rr*34 + cw)*8 + c] = 0;
        }
        if (PRE) {
            #pragma unroll
            for (int k = 0; k < 4; ++k) {
                int uu = tid + k * 512;
                int chalf = uu & 1, o = (uu >> 1) & 127;
                int sub = (uu >> 8) & 3, pjq = (uu >> 10) & 1;
                *(ushort4v*)&wsh[buf][(((pjq*4 + sub)*128 + o)*8) + chalf*4] = wv[k];
            }
        } else {
            #pragma unroll
            for (int k = 0; k < 2; ++k) {
                int pr = tid + k * 512;
                int o = pr >> 3, c = pr & 7;
                float ra[4] = {wa[k].x, wa[k].y, wa[k].z, wa[k].w};
                float rb[4] = {wb[k].x, wb[k].y, wb[k].z, wb[k].w};
                #pragma unroll
                for (int pj2 = 0; pj2 < 2; ++pj2)
                #pragma unroll
                for (int du = 0; du < 2; ++du)
                #pragma unroll
                for (int dv = 0; dv < 2; ++dv) {
                    float val = du ? rb[pj2 + 2*dv] : ra[pj2 + 2*dv];
                    wsh[buf][(((pj2*4 + du*2 + dv)*128 + o)*8) + c] = f2bf(val);
                }
            }
        }
    };

    stage_load(0);
    stage_write(0);
    __syncthreads();

    for (int ch = 0; ch < 32; ++ch) {
        const int cur = ch & 1;
        if (ch + 1 < 32) stage_load(ch + 1);          // issue early (T14)

        short8 bfr[4];
        #pragma unroll
        for (int jj = 0; jj < 4; ++jj) {
            int arow = q*2 + (jj >> 1);
            int b    = (jj & 1)*16 + ln;
            int rr   = arow + (lg >> 1);              // + du
            int cw   = b + pjw + (lg & 1);            // + dv
            bfr[jj]  = *(const short8*)&xsh[cur][(rr*34 + cw)*8];
        }
        #pragma unroll
        for (int i = 0; i < 8; ++i) {
            short8 av = *(const short8*)&wsh[cur][((pjw*4 + lg)*128 + i*16 + ln)*8];
            #pragma unroll
            for (int jj = 0; jj < 4; ++jj)
                acc[i][jj] = __builtin_amdgcn_mfma_f32_16x16x32_bf16(
                                 av, bfr[jj], acc[i][jj], 0, 0, 0);
        }

        if (ch + 1 < 32) stage_write(cur ^ 1);
        __syncthreads();
    }

    // Epilogue. D layout (m89): o = i*16 + lg*4 + r, pixel col = ln.
    #pragma unroll
    for (int i = 0; i < 8; ++i) {
        const f32x4 bv = *(const f32x4*)&bias[i*16 + lg*4];
        #pragma unroll
        for (int jj = 0; jj < 4; ++jj) {
            int arow  = q*2 + (jj >> 1);
            int b     = (jj & 1)*16 + ln;
            int i_out = 2*(a0 + arow) + pi;
            int j_out = 2*b + pjw;
            int o0    = i*16 + lg*4;
            int base  = ((n*128 + o0)*64 + i_out)*64 + j_out;
            #pragma unroll
            for (int r = 0; r < 4; ++r)
                out[base + r*4096] = acc[i][jj][r] + bv[r];
        }
    }
}

extern "C" void kernel_launch(void* const* d_in, const int* in_sizes, int n_in,
                              void* d_out, int out_size, void* d_ws, size_t ws_size,
                              hipStream_t stream) {
    const float* x    = (const float*)d_in[0];
    const float* W    = (const float*)d_in[1];
    const float* bias = (const float*)d_in[2];
    float* out        = (float*)d_out;

    const size_t wp_bytes = 4u * 4u * 128u * 256u * 2u;   // 1 MB
    if (ws_size >= wp_bytes) {
        unsigned short* Wp = (unsigned short*)d_ws;
        prepack_w<<<128, 256, 0, stream>>>(W, Wp);
        tconv_mfma<true><<<256, 512, 0, stream>>>(x, W, Wp, bias, out);
    } else {
        tconv_mfma<false><<<256, 512, 0, stream>>>(x, W, nullptr, bias, out);
    }
}

// Round 4
// 57.862 us; speedup vs baseline: 243.3251x; 1.4657x over previous
//
#include <hip/hip_runtime.h>

// Transposed conv (stride 2, 4x4, pad 2) as bf16 MFMA implicit GEMM, v3.1.
// x: (32,256,32,32) f32, W: (128,256,4,4) OIHW f32, b: (128,), out: (32,128,64,64) f32
// y[n,o,2a+pi,2b+pj] = bias[o] + sum_{c,du,dv} W[o,c,pi+2du,pj+2dv] * x[n,c,a+pi-1+du,b+pj-1+dv]
//
// v3.1: fixes prepack_x halo bug (vp<=33 read one column past the valid input,
// OOB LDS for the last channel group -> absmax 40 at j=63). Valid v = vp-1 in
// [0,32)  =>  interior vp range is [1,32]; vp=0,33 are zero halo.

typedef float  f32x4  __attribute__((ext_vector_type(4)));
typedef short  short8 __attribute__((ext_vector_type(8)));
typedef unsigned short ushort4v __attribute__((ext_vector_type(4)));
typedef unsigned short ushort8v __attribute__((ext_vector_type(8)));

__device__ __forceinline__ unsigned short f2bf(float f) {
    unsigned u = __builtin_bit_cast(unsigned, f);
    u += 0x7fffu + ((u >> 16) & 1u);          // RNE (inputs finite)
    return (unsigned short)(u >> 16);
}

__device__ __forceinline__ void ld_lds16(const unsigned short* g, unsigned short* l) {
    __builtin_amdgcn_global_load_lds(
        (const __attribute__((address_space(1))) unsigned int*)g,
        (__attribute__((address_space(3))) unsigned int*)l,
        16, 0, 0);
}

// ---------------- fast-path layout constants (ushort units) ----------------
#define XP_U 288                 // per u' row: 36 v' * 8 c
#define XP_G 9792                // per (n,g): 34 * XP_U
#define XP_N 313344              // per n: 32 g * XP_G
#define WP_G 8192                // per (pi,g): 2 pj * 4 sub * 128 o * 8 c
#define WP_PI 262144             // 32 g * WP_G

// Wp2[pi][g][pj][sub][o][c8] = bf16(W[o][g*8+c8][pi+2du][pj+2dv]), sub=2du+dv
__global__ __launch_bounds__(256) void prepack_w2(const float* __restrict__ W,
                                                  unsigned short* __restrict__ wp) {
    int t = blockIdx.x * 256 + threadIdx.x;   // (o,c) in [0, 32768)
    int o = t >> 8, c = t & 255;
    int g = c >> 3, c8 = c & 7;
    const float4* src = (const float4*)(W + (size_t)(o * 256 + c) * 16);
    float4 q0 = src[0], q1 = src[1], q2 = src[2], q3 = src[3];
    float rows[4][4] = {{q0.x,q0.y,q0.z,q0.w},{q1.x,q1.y,q1.z,q1.w},
                        {q2.x,q2.y,q2.z,q2.w},{q3.x,q3.y,q3.z,q3.w}};
    #pragma unroll
    for (int pi = 0; pi < 2; ++pi)
    #pragma unroll
    for (int pj = 0; pj < 2; ++pj)
    #pragma unroll
    for (int du = 0; du < 2; ++du)
    #pragma unroll
    for (int dv = 0; dv < 2; ++dv)
        wp[pi*WP_PI + g*WP_G + pj*4096 + (du*2+dv)*1024 + o*8 + c8] =
            f2bf(rows[pi+2*du][pj+2*dv]);
}

// xp[n][g][u'][v'][c8] = bf16(x[n][g*8+c8][u'-1][v'-1]); u'/v' out of range -> 0.
// grid (34 u', 32 n), 256 thr.
__global__ __launch_bounds__(256) void prepack_x(const float* __restrict__ x,
                                                 unsigned short* __restrict__ xp) {
    __shared__ unsigned short xt[256 * 32];   // [c][v] bf16, 16 KB
    const int tid = threadIdx.x;
    const int up  = blockIdx.x;               // u' in [0,34)
    const int n   = blockIdx.y;
    const bool interior = (up >= 1 && up <= 32);

    if (interior) {
        const int u = up - 1;
        #pragma unroll
        for (int k = 0; k < 8; ++k) {
            int idx4 = tid + k * 256;          // [0,2048) float4 units
            int c = idx4 >> 3, v4 = idx4 & 7;
            float4 val = *(const float4*)(x + ((size_t)(n*256 + c)*32 + u)*32 + v4*4);
            ushort4v s = { f2bf(val.x), f2bf(val.y), f2bf(val.z), f2bf(val.w) };
            *(ushort4v*)&xt[c*32 + v4*4] = s;
        }
        __syncthreads();
    }

    #pragma unroll
    for (int s = 0; s < 5; ++s) {
        int id = tid + s * 256;                // (g, v') in [0, 32*36)
        if (id < 1152) {
            int g = id / 36, vp = id % 36;
            ushort8v o8 = {0,0,0,0,0,0,0,0};
            if (interior && vp >= 1 && vp <= 32) {      // FIX: v = vp-1 in [0,32)
                #pragma unroll
                for (int e = 0; e < 8; ++e)
                    o8[e] = xt[(g*8 + e)*32 + (vp - 1)];
            }
            *(ushort8v*)&xp[(size_t)n*XP_N + g*XP_G + up*XP_U + vp*8] = o8;
        }
    }
}

// Main: grid 512 = (pi, aq in [0,8), n) XCD-swizzled; 256 thr = 4 waves (pjw, half).
// Block tile: 128 o x (4 arows x 32 b x 2 pj). Wave: 128 o x 64 px -> 8x4 MFMA tiles.
__global__ __launch_bounds__(256, 3) void tconv_main(
    const unsigned short* __restrict__ xp,
    const unsigned short* __restrict__ wp,
    const float* __restrict__ bias,
    float* __restrict__ out)
{
    // carve: xsh[2][5][36][8] = 2x1440 sh; wsh[2][8 rows][1056 sh] = 2x8448 sh
    __shared__ __align__(16) unsigned short lds[19776];
    unsigned short* xsh0 = lds;
    unsigned short* wsh0 = lds + 2880;

    const int tid  = threadIdx.x;
    const int lane = tid & 63;
    const int w    = tid >> 6;       // wave 0..3
    const int pjw  = w >> 1;
    const int half = w & 1;
    const int lg   = lane >> 4;      // sub = (du,dv)
    const int ln   = lane & 15;
    const int du   = lg >> 1, dv = lg & 1;

    const int bid = blockIdx.x;
    const int wg  = (bid & 7) * 64 + (bid >> 3);   // XCD swizzle (512 % 8 == 0)
    const int n   = wg >> 4;
    const int aq  = (wg >> 1) & 7;
    const int pi  = wg & 1;
    const int a0  = aq * 4;

    const unsigned short* xpb = xp + (size_t)n * XP_N + (a0 + pi) * XP_U;
    const unsigned short* wpb = wp + pi * WP_PI;

    f32x4 acc[8][4];
    #pragma unroll
    for (int i = 0; i < 8; ++i)
        #pragma unroll
        for (int jj = 0; jj < 4; ++jj)
            acc[i][jj] = (f32x4){0.f, 0.f, 0.f, 0.f};

    auto stage = [&](int buf, int ch) {
        unsigned short* wd = wsh0 + buf * 8448;
        unsigned short* xd = xsh0 + buf * 1440;
        const unsigned short* ws = wpb + ch * WP_G;
        const unsigned short* xs = xpb + ch * XP_G;
        // W: 16 KB -> 16 wave-instructions; wave w does rows 2w, 2w+1 (2 halves each)
        #pragma unroll
        for (int s = 0; s < 4; ++s) {
            int r = w * 2 + (s >> 1);
            int h = s & 1;
            ld_lds16(ws + r * 1024 + h * 512 + lane * 8,
                     wd + r * 1056 + h * 512);
        }
        // x: 5 rows x 576 B; wave w does row w, wave 0 also row 4
        if (lane < 36) {
            ld_lds16(xs + w * XP_U + lane * 8, xd + w * 288);
            if (w == 0)
                ld_lds16(xs + 4 * XP_U + lane * 8, xd + 4 * 288);
        }
    };

    stage(0, 0);
    __syncthreads();   // drains vmcnt(0)

    for (int ch = 0; ch < 32; ++ch) {
        const int cur = ch & 1;
        if (ch + 1 < 32) stage(cur ^ 1, ch + 1);   // issue before compute (T14)

        const unsigned short* xb = xsh0 + cur * 1440;
        const unsigned short* wb = wsh0 + cur * 8448;

        short8 bfr[4];
        #pragma unroll
        for (int jj = 0; jj < 4; ++jj) {
            int rr = half * 2 + (jj >> 1) + du;
            int vv = (jj & 1) * 16 + ln + pjw + dv;
            bfr[jj] = *(const short8*)&xb[(rr * 36 + vv) * 8];
        }
        #pragma unroll
        for (int i = 0; i < 8; ++i) {
            short8 av = *(const short8*)&wb[(pjw * 4 + lg) * 1056 + (i * 16 + ln) * 8];
            #pragma unroll
            for (int jj = 0; jj < 4; ++jj)
                acc[i][jj] = __builtin_amdgcn_mfma_f32_16x16x32_bf16(
                                 av, bfr[jj], acc[i][jj], 0, 0, 0);
        }
        __syncthreads();   // next-buf loads landed; this-buf reads done everywhere
    }

    // Epilogue: LDS transpose -> coalesced float4 stores.
    // epi[o_l(16)][ar(4)][pj(2)][33 (32 b + 1 pad)] f32 = 16896 B, overlays lds.
    float* epi = (float*)lds;
    #pragma unroll
    for (int i = 0; i < 8; ++i) {
        __syncthreads();
        f32x4 bv = *(const f32x4*)&bias[i * 16 + lg * 4];
        #pragma unroll
        for (int jj = 0; jj < 4; ++jj) {
            int ar = half * 2 + (jj >> 1);
            int b  = (jj & 1) * 16 + ln;
            #pragma unroll
            for (int r = 0; r < 4; ++r)
                epi[((lg * 4 + r) * 8 + ar * 2 + pjw) * 33 + b] = acc[i][jj][r] + bv[r];
        }
        __syncthreads();
        #pragma unroll
        for (int k = 0; k < 4; ++k) {
            int f   = tid + k * 256;     // [0,1024) float4-store ids
            int row = f >> 4;            // o_l*4 + ar
            int q   = f & 15;
            float4 v;
            v.x = epi[(row * 2 + 0) * 33 + q * 2 + 0];
            v.y = epi[(row * 2 + 1) * 33 + q * 2 + 0];
            v.z = epi[(row * 2 + 0) * 33 + q * 2 + 1];
            v.w = epi[(row * 2 + 1) * 33 + q * 2 + 1];
            int o     = i * 16 + (row >> 2);
            int i_out = 2 * (a0 + (row & 3)) + pi;
            *(float4*)&out[(((size_t)n * 128 + o) * 64 + i_out) * 64 + q * 4] = v;
        }
    }
}

// =================== fallback: round-2 kernel (proven) ===================
__global__ __launch_bounds__(256) void prepack_w(const float* __restrict__ W,
                                                 unsigned short* __restrict__ Wp) {
    int t = blockIdx.x * 256 + threadIdx.x;
    int o = t >> 8, c = t & 255;
    const float4* src = (const float4*)(W + (size_t)(o * 256 + c) * 16);
    float4 q0 = src[0], q1 = src[1], q2 = src[2], q3 = src[3];
    float rows[4][4] = {{q0.x,q0.y,q0.z,q0.w},{q1.x,q1.y,q1.z,q1.w},
                        {q2.x,q2.y,q2.z,q2.w},{q3.x,q3.y,q3.z,q3.w}};
    #pragma unroll
    for (int pi = 0; pi < 2; ++pi)
    #pragma unroll
    for (int pj = 0; pj < 2; ++pj)
    #pragma unroll
    for (int du = 0; du < 2; ++du)
    #pragma unroll
    for (int dv = 0; dv < 2; ++dv)
        Wp[((((pi*2+pj)*4 + du*2+dv)*128 + o)*256) + c] = f2bf(rows[pi+2*du][pj+2*dv]);
}

template<bool PRE>
__global__ __launch_bounds__(512, 2) void tconv_mfma(
    const float* __restrict__ x, const float* __restrict__ W,
    const unsigned short* __restrict__ Wp, const float* __restrict__ bias,
    float* __restrict__ out)
{
    __shared__ __align__(16) unsigned short xsh[2][9 * 34 * 8];
    __shared__ __align__(16) unsigned short wsh[2][2 * 4 * 128 * 8];

    const int tid = threadIdx.x;
    const int bid = blockIdx.x;
    const int pi  = bid & 1;
    const int aq  = (bid >> 1) & 3;
    const int n   = bid >> 3;
    const int a0  = aq * 8;
    const int u0  = a0 + pi - 1;

    const int l   = tid & 63;
    const int w   = tid >> 6;
    const int pjw = w >> 2;
    const int q   = w & 3;
    const int lg  = l >> 4;
    const int ln  = l & 15;

    const int sv = tid & 31;
    const int sg = tid >> 5;

    f32x4 acc[8][4];
    #pragma unroll
    for (int i = 0; i < 8; ++i)
        #pragma unroll
        for (int jj = 0; jj < 4; ++jj)
            acc[i][jj] = (f32x4){0.f, 0.f, 0.f, 0.f};

    float    xv[5];
    ushort4v wv[4];
    float4   wa[2], wb[2];

    auto stage_load = [&](int ch) {
        const int c0 = ch * 8;
        #pragma unroll
        for (int s = 0; s < 5; ++s) {
            int p = sg * 5 + s;
            if (p < 72) {
                int c = p & 7, rr = p >> 3;
                int u = u0 + rr;
                xv[s] = ((unsigned)u < 32u)
                      ? x[((n*256 + c0 + c)*32 + u)*32 + sv] : 0.f;
            }
        }
        if (PRE) {
            #pragma unroll
            for (int k = 0; k < 4; ++k) {
                int uu = tid + k * 512;
                int chalf = uu & 1, o = (uu >> 1) & 127;
                int sub = (uu >> 8) & 3, pjq = (uu >> 10) & 1;
                wv[k] = *(const ushort4v*)&Wp[(((pi*2 + pjq)*4 + sub)*128 + o)*256
                                              + c0 + chalf*4];
            }
        } else {
            #pragma unroll
            for (int k = 0; k < 2; ++k) {
                int pr = tid + k * 512;
                int o = pr >> 3, c = pr & 7;
                const float* base = W + ((o*256 + c0 + c) << 4) + pi*4;
                wa[k] = *(const float4*)base;
                wb[k] = *(const float4*)(base + 8);
            }
        }
    };

    auto stage_write = [&](int buf) {
        #pragma unroll
        for (int s = 0; s < 5; ++s) {
            int p = sg * 5 + s;
            if (p < 72) {
                int c = p & 7, rr = p >> 3;
                xsh[buf][(rr*34 + sv + 1)*8 + c] = f2bf(xv[s]);
            }
        }
        if (tid < 144) {
            int pr = tid >> 1;
            int rr = pr >> 3, c = pr & 7;
            int cw = (tid & 1) * 33;
            xsh[buf][(rr*34 + cw)*8 + c] = 0;
        }
        if (PRE) {
            #pragma unroll
            for (int k = 0; k < 4; ++k) {
                int uu = tid + k * 512;
                int chalf = uu & 1, o = (uu >> 1) & 127;
                int sub = (uu >> 8) & 3, pjq = (uu >> 10) & 1;
                *(ushort4v*)&wsh[buf][(((pjq*4 + sub)*128 + o)*8) + chalf*4] = wv[k];
            }
        } else {
            #pragma unroll
            for (int k = 0; k < 2; ++k) {
                int pr = tid + k * 512;
                int o = pr >> 3, c = pr & 7;
                float ra[4] = {wa[k].x, wa[k].y, wa[k].z, wa[k].w};
                float rb[4] = {wb[k].x, wb[k].y, wb[k].z, wb[k].w};
                #pragma unroll
                for (int pj2 = 0; pj2 < 2; ++pj2)
                #pragma unroll
                for (int duu = 0; duu < 2; ++duu)
                #pragma unroll
                for (int dvv = 0; dvv < 2; ++dvv) {
                    float val = duu ? rb[pj2 + 2*dvv] : ra[pj2 + 2*dvv];
                    wsh[buf][(((pj2*4 + duu*2 + dvv)*128 + o)*8) + c] = f2bf(val);
                }
            }
        }
    };

    stage_load(0);
    stage_write(0);
    __syncthreads();

    for (int ch = 0; ch < 32; ++ch) {
        const int cur = ch & 1;
        if (ch + 1 < 32) stage_load(ch + 1);

        short8 bfr[4];
        #pragma unroll
        for (int jj = 0; jj < 4; ++jj) {
            int arow = q*2 + (jj >> 1);
            int b    = (jj & 1)*16 + ln;
            int rr   = arow + (lg >> 1);
            int cw   = b + pjw + (lg & 1);
            bfr[jj]  = *(const short8*)&xsh[cur][(rr*34 + cw)*8];
        }
        #pragma unroll
        for (int i = 0; i < 8; ++i) {
            short8 av = *(const short8*)&wsh[cur][((pjw*4 + lg)*128 + i*16 + ln)*8];
            #pragma unroll
            for (int jj = 0; jj < 4; ++jj)
                acc[i][jj] = __builtin_amdgcn_mfma_f32_16x16x32_bf16(
                                 av, bfr[jj], acc[i][jj], 0, 0, 0);
        }

        if (ch + 1 < 32) stage_write(cur ^ 1);
        __syncthreads();
    }

    #pragma unroll
    for (int i = 0; i < 8; ++i) {
        const f32x4 bv = *(const f32x4*)&bias[i*16 + lg*4];
        #pragma unroll
        for (int jj = 0; jj < 4; ++jj) {
            int arow  = q*2 + (jj >> 1);
            int b     = (jj & 1)*16 + ln;
            int i_out = 2*(a0 + arow) + pi;
            int j_out = 2*b + pjw;
            int o0    = i*16 + lg*4;
            int base  = ((n*128 + o0)*64 + i_out)*64 + j_out;
            #pragma unroll
            for (int r = 0; r < 4; ++r)
                out[base + r*4096] = acc[i][jj][r] + bv[r];
        }
    }
}

extern "C" void kernel_launch(void* const* d_in, const int* in_sizes, int n_in,
                              void* d_out, int out_size, void* d_ws, size_t ws_size,
                              hipStream_t stream) {
    const float* x    = (const float*)d_in[0];
    const float* W    = (const float*)d_in[1];
    const float* bias = (const float*)d_in[2];
    float* out        = (float*)d_out;

    const size_t wp2_bytes = (size_t)2 * WP_PI * 2;          // 1 MB
    const size_t xp_bytes  = (size_t)32 * XP_N * 2;          // ~20 MB
    if (ws_size >= wp2_bytes + xp_bytes) {
        unsigned short* wp2 = (unsigned short*)d_ws;
        unsigned short* xpp = (unsigned short*)((char*)d_ws + wp2_bytes);
        prepack_w2<<<128, 256, 0, stream>>>(W, wp2);
        prepack_x<<<dim3(34, 32), 256, 0, stream>>>(x, xpp);
        tconv_main<<<512, 256, 0, stream>>>(xpp, wp2, bias, out);
    } else if (ws_size >= (size_t)4*4*128*256*2) {
        unsigned short* Wp = (unsigned short*)d_ws;
        prepack_w<<<128, 256, 0, stream>>>(W, Wp);
        tconv_mfma<true><<<256, 512, 0, stream>>>(x, W, Wp, bias, out);
    } else {
        tconv_mfma<false><<<256, 512, 0, stream>>>(x, W, nullptr, bias, out);
    }
}

// Round 5
// 55.478 us; speedup vs baseline: 253.7814x; 1.0430x over previous
//
#include <hip/hip_runtime.h>

// Transposed conv (stride 2, 4x4, pad 2) as bf16 MFMA implicit GEMM, v4.
// x: (32,256,32,32) f32, W: (128,256,4,4) OIHW f32, b: (128,), out: (32,128,64,64) f32
// y[n,o,2a+pi,2b+pj] = bias[o] + sum_{c,du,dv} W[o,c,pi+2du,pj+2dv] * x[n,c,a+pi-1+du,b+pj-1+dv]
//
// v4: T3/T4 counted-vmcnt pipeline. 4 LDS buffers, 3-deep global_load_lds
// prefetch, s_waitcnt vmcnt(12) (never 0) + raw s_barrier per chunk. Each wave
// issues exactly 6 DMA loads per stage (wave-uniform vmcnt accounting).
// Invariant: a wave passing barrier(ch) has consumed buf[(ch-1)&3] (lgkm-waited
// MFMA before barrier), so stage(ch+3) -> buf[(ch+3)&3] == buf[(ch-1)&3] is safe.

typedef float  f32x4  __attribute__((ext_vector_type(4)));
typedef short  short8 __attribute__((ext_vector_type(8)));
typedef unsigned short ushort4v __attribute__((ext_vector_type(4)));
typedef unsigned short ushort8v __attribute__((ext_vector_type(8)));

__device__ __forceinline__ unsigned short f2bf(float f) {
    unsigned u = __builtin_bit_cast(unsigned, f);
    u += 0x7fffu + ((u >> 16) & 1u);          // RNE (inputs finite)
    return (unsigned short)(u >> 16);
}

__device__ __forceinline__ void ld_lds16(const unsigned short* g, unsigned short* l) {
    __builtin_amdgcn_global_load_lds(
        (const __attribute__((address_space(1))) unsigned int*)g,
        (__attribute__((address_space(3))) unsigned int*)l,
        16, 0, 0);
}

// ---------------- fast-path layout constants (ushort units) ----------------
#define XP_U 288                 // per u' row: 36 v' * 8 c
#define XP_G 9792                // per (n,g): 34 * XP_U
#define XP_N 313344              // per n: 32 g * XP_G
#define WP_G 8192                // per (pi,g): 2 pj * 4 sub * 128 o * 8 c
#define WP_PI 262144             // 32 g * WP_G

// Wp2[pi][g][pj][sub][o][c8] = bf16(W[o][g*8+c8][pi+2du][pj+2dv]), sub=2du+dv
__global__ __launch_bounds__(256) void prepack_w2(const float* __restrict__ W,
                                                  unsigned short* __restrict__ wp) {
    int t = blockIdx.x * 256 + threadIdx.x;   // (o,c) in [0, 32768)
    int o = t >> 8, c = t & 255;
    int g = c >> 3, c8 = c & 7;
    const float4* src = (const float4*)(W + (size_t)(o * 256 + c) * 16);
    float4 q0 = src[0], q1 = src[1], q2 = src[2], q3 = src[3];
    float rows[4][4] = {{q0.x,q0.y,q0.z,q0.w},{q1.x,q1.y,q1.z,q1.w},
                        {q2.x,q2.y,q2.z,q2.w},{q3.x,q3.y,q3.z,q3.w}};
    #pragma unroll
    for (int pi = 0; pi < 2; ++pi)
    #pragma unroll
    for (int pj = 0; pj < 2; ++pj)
    #pragma unroll
    for (int du = 0; du < 2; ++du)
    #pragma unroll
    for (int dv = 0; dv < 2; ++dv)
        wp[pi*WP_PI + g*WP_G + pj*4096 + (du*2+dv)*1024 + o*8 + c8] =
            f2bf(rows[pi+2*du][pj+2*dv]);
}

// xp[n][g][u'][v'][c8] = bf16(x[n][g*8+c8][u'-1][v'-1]); u'/v' out of range -> 0.
__global__ __launch_bounds__(256) void prepack_x(const float* __restrict__ x,
                                                 unsigned short* __restrict__ xp) {
    __shared__ unsigned short xt[256 * 32];   // [c][v] bf16, 16 KB
    const int tid = threadIdx.x;
    const int up  = blockIdx.x;               // u' in [0,34)
    const int n   = blockIdx.y;
    const bool interior = (up >= 1 && up <= 32);

    if (interior) {
        const int u = up - 1;
        #pragma unroll
        for (int k = 0; k < 8; ++k) {
            int idx4 = tid + k * 256;          // [0,2048) float4 units
            int c = idx4 >> 3, v4 = idx4 & 7;
            float4 val = *(const float4*)(x + ((size_t)(n*256 + c)*32 + u)*32 + v4*4);
            ushort4v s = { f2bf(val.x), f2bf(val.y), f2bf(val.z), f2bf(val.w) };
            *(ushort4v*)&xt[c*32 + v4*4] = s;
        }
        __syncthreads();
    }

    #pragma unroll
    for (int s = 0; s < 5; ++s) {
        int id = tid + s * 256;                // (g, v') in [0, 32*36)
        if (id < 1152) {
            int g = id / 36, vp = id % 36;
            ushort8v o8 = {0,0,0,0,0,0,0,0};
            if (interior && vp >= 1 && vp <= 32) {      // v = vp-1 in [0,32)
                #pragma unroll
                for (int e = 0; e < 8; ++e)
                    o8[e] = xt[(g*8 + e)*32 + (vp - 1)];
            }
            *(ushort8v*)&xp[(size_t)n*XP_N + g*XP_G + up*XP_U + vp*8] = o8;
        }
    }
}

// Main: grid 512 = (pi, aq in [0,8), n) XCD-swizzled; 256 thr = 4 waves (pjw, half).
// Block tile: 128 o x (4 arows x 32 b x 2 pj). Wave: 128 o x 64 px -> 8x4 MFMA tiles.
__global__ __launch_bounds__(256, 2) void tconv_main(
    const unsigned short* __restrict__ xp,
    const unsigned short* __restrict__ wp,
    const float* __restrict__ bias,
    float* __restrict__ out)
{
    // 4 buffers: xsh[4][1440] then wsh[4][8448]  -> 39552 sh = 79104 B
    __shared__ __align__(16) unsigned short lds[39552];
    unsigned short* xsh0 = lds;               // buf stride 1440
    unsigned short* wsh0 = lds + 4 * 1440;    // buf stride 8448

    const int tid  = threadIdx.x;
    const int lane = tid & 63;
    const int w    = tid >> 6;       // wave 0..3
    const int pjw  = w >> 1;
    const int half = w & 1;
    const int lg   = lane >> 4;      // sub = (du,dv)
    const int ln   = lane & 15;
    const int du   = lg >> 1, dv = lg & 1;

    const int bid = blockIdx.x;
    const int wg  = (bid & 7) * 64 + (bid >> 3);   // XCD swizzle (512 % 8 == 0)
    const int n   = wg >> 4;
    const int aq  = (wg >> 1) & 7;
    const int pi  = wg & 1;
    const int a0  = aq * 4;

    const unsigned short* xpb = xp + (size_t)n * XP_N + (a0 + pi) * XP_U;
    const unsigned short* wpb = wp + pi * WP_PI;

    f32x4 acc[8][4];
    #pragma unroll
    for (int i = 0; i < 8; ++i)
        #pragma unroll
        for (int jj = 0; jj < 4; ++jj)
            acc[i][jj] = (f32x4){0.f, 0.f, 0.f, 0.f};

    // Exactly 6 DMA loads per wave per stage (uniform vmcnt accounting):
    // 4 W-loads + 1 full x-row (36 lanes) + 1 quarter of x-row 4 (9 lanes).
    auto stage = [&](int buf, int ch) {
        unsigned short* wd = wsh0 + buf * 8448;
        unsigned short* xd = xsh0 + buf * 1440;
        const unsigned short* ws = wpb + ch * WP_G;
        const unsigned short* xs = xpb + ch * XP_G;
        #pragma unroll
        for (int s = 0; s < 4; ++s) {
            int r = w * 2 + (s >> 1);
            int h = s & 1;
            ld_lds16(ws + r * 1024 + h * 512 + lane * 8,
                     wd + r * 1056 + h * 512);
        }
        if (lane < 36)
            ld_lds16(xs + w * XP_U + lane * 8, xd + w * 288);
        if (lane < 9)
            ld_lds16(xs + 4 * XP_U + (w * 9 + lane) * 8, xd + 4 * 288 + w * 72);
    };

    stage(0, 0);
    stage(1, 1);
    stage(2, 2);      // 18 loads in flight per wave

    for (int ch = 0; ch < 32; ++ch) {
        const int cur = ch & 3;
        // Wait until stage(ch) landed (stages ch+1, ch+2 stay in flight = 12),
        // then sync so everyone's stage(ch) is visible. NEVER vmcnt(0) here.
        __builtin_amdgcn_sched_barrier(0);
        asm volatile("s_waitcnt vmcnt(12)" ::: "memory");
        __builtin_amdgcn_s_barrier();
        __builtin_amdgcn_sched_barrier(0);

        const unsigned short* xb = xsh0 + cur * 1440;
        const unsigned short* wb = wsh0 + cur * 8448;

        short8 bfr[4];
        #pragma unroll
        for (int jj = 0; jj < 4; ++jj) {
            int rr = half * 2 + (jj >> 1) + du;
            int vv = (jj & 1) * 16 + ln + pjw + dv;
            bfr[jj] = *(const short8*)&xb[(rr * 36 + vv) * 8];
        }

        // Prefetch stage(ch+3) into buf[(ch+3)&3] (== buf[(ch-1)&3], safe per
        // invariant). Tail (ch+3 >= 32): dummy re-stage of chunk (ch+3)&31 into
        // a buffer not read again -> keeps per-iter vmcnt uniform, branch-free.
        const int chs = ch + 3;
        stage(chs & 3, chs & 31);

        #pragma unroll
        for (int i = 0; i < 8; ++i) {
            short8 av = *(const short8*)&wb[(pjw * 4 + lg) * 1056 + (i * 16 + ln) * 8];
            #pragma unroll
            for (int jj = 0; jj < 4; ++jj)
                acc[i][jj] = __builtin_amdgcn_mfma_f32_16x16x32_bf16(
                                 av, bfr[jj], acc[i][jj], 0, 0, 0);
        }
    }

    __syncthreads();   // drains dummy DMA (vmcnt 0) before LDS reuse

    // Epilogue: LDS transpose -> coalesced float4 stores.
    // epi[o_l*4+r (16..)][ar(4)*2+pj][33] f32 = 16896 B, overlays lds.
    float* epi = (float*)lds;
    #pragma unroll
    for (int i = 0; i < 8; ++i) {
        __syncthreads();
        f32x4 bv = *(const f32x4*)&bias[i * 16 + lg * 4];
        #pragma unroll
        for (int jj = 0; jj < 4; ++jj) {
            int ar = half * 2 + (jj >> 1);
            int b  = (jj & 1) * 16 + ln;
            #pragma unroll
            for (int r = 0; r < 4; ++r)
                epi[((lg * 4 + r) * 8 + ar * 2 + pjw) * 33 + b] = acc[i][jj][r] + bv[r];
        }
        __syncthreads();
        #pragma unroll
        for (int k = 0; k < 4; ++k) {
            int f   = tid + k * 256;     // [0,1024) float4-store ids
            int row = f >> 4;            // o_l*4 + ar
            int q   = f & 15;
            float4 v;
            v.x = epi[(row * 2 + 0) * 33 + q * 2 + 0];
            v.y = epi[(row * 2 + 1) * 33 + q * 2 + 0];
            v.z = epi[(row * 2 + 0) * 33 + q * 2 + 1];
            v.w = epi[(row * 2 + 1) * 33 + q * 2 + 1];
            int o     = i * 16 + (row >> 2);
            int i_out = 2 * (a0 + (row & 3)) + pi;
            *(float4*)&out[(((size_t)n * 128 + o) * 64 + i_out) * 64 + q * 4] = v;
        }
    }
}

// =================== fallback: round-2 kernel (proven) ===================
__global__ __launch_bounds__(256) void prepack_w(const float* __restrict__ W,
                                                 unsigned short* __restrict__ Wp) {
    int t = blockIdx.x * 256 + threadIdx.x;
    int o = t >> 8, c = t & 255;
    const float4* src = (const float4*)(W + (size_t)(o * 256 + c) * 16);
    float4 q0 = src[0], q1 = src[1], q2 = src[2], q3 = src[3];
    float rows[4][4] = {{q0.x,q0.y,q0.z,q0.w},{q1.x,q1.y,q1.z,q1.w},
                        {q2.x,q2.y,q2.z,q2.w},{q3.x,q3.y,q3.z,q3.w}};
    #pragma unroll
    for (int pi = 0; pi < 2; ++pi)
    #pragma unroll
    for (int pj = 0; pj < 2; ++pj)
    #pragma unroll
    for (int du = 0; du < 2; ++du)
    #pragma unroll
    for (int dv = 0; dv < 2; ++dv)
        Wp[((((pi*2+pj)*4 + du*2+dv)*128 + o)*256) + c] = f2bf(rows[pi+2*du][pj+2*dv]);
}

template<bool PRE>
__global__ __launch_bounds__(512, 2) void tconv_mfma(
    const float* __restrict__ x, const float* __restrict__ W,
    const unsigned short* __restrict__ Wp, const float* __restrict__ bias,
    float* __restrict__ out)
{
    __shared__ __align__(16) unsigned short xsh[2][9 * 34 * 8];
    __shared__ __align__(16) unsigned short wsh[2][2 * 4 * 128 * 8];

    const int tid = threadIdx.x;
    const int bid = blockIdx.x;
    const int pi  = bid & 1;
    const int aq  = (bid >> 1) & 3;
    const int n   = bid >> 3;
    const int a0  = aq * 8;
    const int u0  = a0 + pi - 1;

    const int l   = tid & 63;
    const int w   = tid >> 6;
    const int pjw = w >> 2;
    const int q   = w & 3;
    const int lg  = l >> 4;
    const int ln  = l & 15;

    const int sv = tid & 31;
    const int sg = tid >> 5;

    f32x4 acc[8][4];
    #pragma unroll
    for (int i = 0; i < 8; ++i)
        #pragma unroll
        for (int jj = 0; jj < 4; ++jj)
            acc[i][jj] = (f32x4){0.f, 0.f, 0.f, 0.f};

    float    xv[5];
    ushort4v wv[4];
    float4   wa[2], wb[2];

    auto stage_load = [&](int ch) {
        const int c0 = ch * 8;
        #pragma unroll
        for (int s = 0; s < 5; ++s) {
            int p = sg * 5 + s;
            if (p < 72) {
                int c = p & 7, rr = p >> 3;
                int u = u0 + rr;
                xv[s] = ((unsigned)u < 32u)
                      ? x[((n*256 + c0 + c)*32 + u)*32 + sv] : 0.f;
            }
        }
        if (PRE) {
            #pragma unroll
            for (int k = 0; k < 4; ++k) {
                int uu = tid + k * 512;
                int chalf = uu & 1, o = (uu >> 1) & 127;
                int sub = (uu >> 8) & 3, pjq = (uu >> 10) & 1;
                wv[k] = *(const ushort4v*)&Wp[(((pi*2 + pjq)*4 + sub)*128 + o)*256
                                              + c0 + chalf*4];
            }
        } else {
            #pragma unroll
            for (int k = 0; k < 2; ++k) {
                int pr = tid + k * 512;
                int o = pr >> 3, c = pr & 7;
                const float* base = W + ((o*256 + c0 + c) << 4) + pi*4;
                wa[k] = *(const float4*)base;
                wb[k] = *(const float4*)(base + 8);
            }
        }
    };

    auto stage_write = [&](int buf) {
        #pragma unroll
        for (int s = 0; s < 5; ++s) {
            int p = sg * 5 + s;
            if (p < 72) {
                int c = p & 7, rr = p >> 3;
                xsh[buf][(rr*34 + sv + 1)*8 + c] = f2bf(xv[s]);
            }
        }
        if (tid < 144) {
            int pr = tid >> 1;
            int rr = pr >> 3, c = pr & 7;
            int cw = (tid & 1) * 33;
            xsh[buf][(rr*34 + cw)*8 + c] = 0;
        }
        if (PRE) {
            #pragma unroll
            for (int k = 0; k < 4; ++k) {
                int uu = tid + k * 512;
                int chalf = uu & 1, o = (uu >> 1) & 127;
                int sub = (uu >> 8) & 3, pjq = (uu >> 10) & 1;
                *(ushort4v*)&wsh[buf][(((pjq*4 + sub)*128 + o)*8) + chalf*4] = wv[k];
            }
        } else {
            #pragma unroll
            for (int k = 0; k < 2; ++k) {
                int pr = tid + k * 512;
                int o = pr >> 3, c = pr & 7;
                float ra[4] = {wa[k].x, wa[k].y, wa[k].z, wa[k].w};
                float rb[4] = {wb[k].x, wb[k].y, wb[k].z, wb[k].w};
                #pragma unroll
                for (int pj2 = 0; pj2 < 2; ++pj2)
                #pragma unroll
                for (int duu = 0; duu < 2; ++duu)
                #pragma unroll
                for (int dvv = 0; dvv < 2; ++dvv) {
                    float val = duu ? rb[pj2 + 2*dvv] : ra[pj2 + 2*dvv];
                    wsh[buf][(((pj2*4 + duu*2 + dvv)*128 + o)*8) + c] = f2bf(val);
                }
            }
        }
    };

    stage_load(0);
    stage_write(0);
    __syncthreads();

    for (int ch = 0; ch < 32; ++ch) {
        const int cur = ch & 1;
        if (ch + 1 < 32) stage_load(ch + 1);

        short8 bfr[4];
        #pragma unroll
        for (int jj = 0; jj < 4; ++jj) {
            int arow = q*2 + (jj >> 1);
            int b    = (jj & 1)*16 + ln;
            int rr   = arow + (lg >> 1);
            int cw   = b + pjw + (lg & 1);
            bfr[jj]  = *(const short8*)&xsh[cur][(rr*34 + cw)*8];
        }
        #pragma unroll
        for (int i = 0; i < 8; ++i) {
            short8 av = *(const short8*)&wsh[cur][((pjw*4 + lg)*128 + i*16 + ln)*8];
            #pragma unroll
            for (int jj = 0; jj < 4; ++jj)
                acc[i][jj] = __builtin_amdgcn_mfma_f32_16x16x32_bf16(
                                 av, bfr[jj], acc[i][jj], 0, 0, 0);
        }

        if (ch + 1 < 32) stage_write(cur ^ 1);
        __syncthreads();
    }

    #pragma unroll
    for (int i = 0; i < 8; ++i) {
        const f32x4 bv = *(const f32x4*)&bias[i*16 + lg*4];
        #pragma unroll
        for (int jj = 0; jj < 4; ++jj) {
            int arow  = q*2 + (jj >> 1);
            int b     = (jj & 1)*16 + ln;
            int i_out = 2*(a0 + arow) + pi;
            int j_out = 2*b + pjw;
            int o0    = i*16 + lg*4;
            int base  = ((n*128 + o0)*64 + i_out)*64 + j_out;
            #pragma unroll
            for (int r = 0; r < 4; ++r)
                out[base + r*4096] = acc[i][jj][r] + bv[r];
        }
    }
}

extern "C" void kernel_launch(void* const* d_in, const int* in_sizes, int n_in,
                              void* d_out, int out_size, void* d_ws, size_t ws_size,
                              hipStream_t stream) {
    const float* x    = (const float*)d_in[0];
    const float* W    = (const float*)d_in[1];
    const float* bias = (const float*)d_in[2];
    float* out        = (float*)d_out;

    const size_t wp2_bytes = (size_t)2 * WP_PI * 2;          // 1 MB
    const size_t xp_bytes  = (size_t)32 * XP_N * 2;          // ~20 MB
    if (ws_size >= wp2_bytes + xp_bytes) {
        unsigned short* wp2 = (unsigned short*)d_ws;
        unsigned short* xpp = (unsigned short*)((char*)d_ws + wp2_bytes);
        prepack_w2<<<128, 256, 0, stream>>>(W, wp2);
        prepack_x<<<dim3(34, 32), 256, 0, stream>>>(x, xpp);
        tconv_main<<<512, 256, 0, stream>>>(xpp, wp2, bias, out);
    } else if (ws_size >= (size_t)4*4*128*256*2) {
        unsigned short* Wp = (unsigned short*)d_ws;
        prepack_w<<<128, 256, 0, stream>>>(W, Wp);
        tconv_mfma<true><<<256, 512, 0, stream>>>(x, W, Wp, bias, out);
    } else {
        tconv_mfma<false><<<256, 512, 0, stream>>>(x, W, nullptr, bias, out);
    }
}

// Round 6
// 55.325 us; speedup vs baseline: 254.4838x; 1.0028x over previous
//
#include <hip/hip_runtime.h>

// Transposed conv (stride 2, 4x4, pad 2) as bf16 MFMA implicit GEMM, v5.
// x: (32,256,32,32) f32, W: (128,256,4,4) OIHW f32, b: (128,), out: (32,128,64,64) f32
// y[n,o,2a+pi,2b+pj] = bias[o] + sum_{c,du,dv} W[o,c,pi+2du,pj+2dv] * x[n,c,a+pi-1+du,b+pj-1+dv]
//
// v5: x B-fragments load global->VGPR directly (xp is L3-resident; per-lane
// contiguous), killing the x LDS stage + the 4 conflicting x ds_reads per
// chunk. W keeps the 4-buffer global_load_lds pipeline (prefetch distance 3).
// x-frags ping-pong between two static register slots (distance 2,
// issue-after-consume). vmcnt ledger: each body issues 4 W-lds then 4 x-loads;
// steady-state wait vmcnt(8); tail waits 8,8,4,0. W LDS sub-stride = 1040 sh
// (2080 B = 8-bank phase step) -> balanced 8-per-bank b128 reads, no conflict.

typedef float  f32x4  __attribute__((ext_vector_type(4)));
typedef short  short8 __attribute__((ext_vector_type(8)));
typedef unsigned short ushort4v __attribute__((ext_vector_type(4)));
typedef unsigned short ushort8v __attribute__((ext_vector_type(8)));

__device__ __forceinline__ unsigned short f2bf(float f) {
    unsigned u = __builtin_bit_cast(unsigned, f);
    u += 0x7fffu + ((u >> 16) & 1u);          // RNE (inputs finite)
    return (unsigned short)(u >> 16);
}

__device__ __forceinline__ void ld_lds16(const unsigned short* g, unsigned short* l) {
    __builtin_amdgcn_global_load_lds(
        (const __attribute__((address_space(1))) unsigned int*)g,
        (__attribute__((address_space(3))) unsigned int*)l,
        16, 0, 0);
}

// ---------------- layout constants (ushort units) ----------------
#define XP_U 288                 // per u' row: 36 v' * 8 c
#define XP_G 9792                // per (n,g): 34 * XP_U
#define XP_N 313344              // per n: 32 g * XP_G
#define WP_G 8192                // per (pi,g): 2 pj * 4 sub * 128 o * 8 c
#define WP_PI 262144             // 32 g * WP_G
#define WROW 1040                // LDS sh-stride per (pj,sub) row (1024 + 16 pad)
#define WBUFS 8320               // 8 * WROW per buffer

// Wp2[pi][g][pj][sub][o][c8] = bf16(W[o][g*8+c8][pi+2du][pj+2dv]), sub=2du+dv
__global__ __launch_bounds__(256) void prepack_w2(const float* __restrict__ W,
                                                  unsigned short* __restrict__ wp) {
    int t = blockIdx.x * 256 + threadIdx.x;   // (o,c) in [0, 32768)
    int o = t >> 8, c = t & 255;
    int g = c >> 3, c8 = c & 7;
    const float4* src = (const float4*)(W + (size_t)(o * 256 + c) * 16);
    float4 q0 = src[0], q1 = src[1], q2 = src[2], q3 = src[3];
    float rows[4][4] = {{q0.x,q0.y,q0.z,q0.w},{q1.x,q1.y,q1.z,q1.w},
                        {q2.x,q2.y,q2.z,q2.w},{q3.x,q3.y,q3.z,q3.w}};
    #pragma unroll
    for (int pi = 0; pi < 2; ++pi)
    #pragma unroll
    for (int pj = 0; pj < 2; ++pj)
    #pragma unroll
    for (int du = 0; du < 2; ++du)
    #pragma unroll
    for (int dv = 0; dv < 2; ++dv)
        wp[pi*WP_PI + g*WP_G + pj*4096 + (du*2+dv)*1024 + o*8 + c8] =
            f2bf(rows[pi+2*du][pj+2*dv]);
}

// xp[n][g][u'][v'][c8] = bf16(x[n][g*8+c8][u'-1][v'-1]); u'/v' out of range -> 0.
__global__ __launch_bounds__(256) void prepack_x(const float* __restrict__ x,
                                                 unsigned short* __restrict__ xp) {
    __shared__ unsigned short xt[256 * 32];   // [c][v] bf16, 16 KB
    const int tid = threadIdx.x;
    const int up  = blockIdx.x;               // u' in [0,34)
    const int n   = blockIdx.y;
    const bool interior = (up >= 1 && up <= 32);

    if (interior) {
        const int u = up - 1;
        #pragma unroll
        for (int k = 0; k < 8; ++k) {
            int idx4 = tid + k * 256;          // [0,2048) float4 units
            int c = idx4 >> 3, v4 = idx4 & 7;
            float4 val = *(const float4*)(x + ((size_t)(n*256 + c)*32 + u)*32 + v4*4);
            ushort4v s = { f2bf(val.x), f2bf(val.y), f2bf(val.z), f2bf(val.w) };
            *(ushort4v*)&xt[c*32 + v4*4] = s;
        }
        __syncthreads();
    }

    #pragma unroll
    for (int s = 0; s < 5; ++s) {
        int id = tid + s * 256;                // (g, v') in [0, 32*36)
        if (id < 1152) {
            int g = id / 36, vp = id % 36;
            ushort8v o8 = {0,0,0,0,0,0,0,0};
            if (interior && vp >= 1 && vp <= 32) {      // v = vp-1 in [0,32)
                #pragma unroll
                for (int e = 0; e < 8; ++e)
                    o8[e] = xt[(g*8 + e)*32 + (vp - 1)];
            }
            *(ushort8v*)&xp[(size_t)n*XP_N + g*XP_G + up*XP_U + vp*8] = o8;
        }
    }
}

// Main: grid 512 = (pi, aq in [0,8), n) XCD-swizzled; 256 thr = 4 waves (pjw, half).
// Block tile: 128 o x (4 arows x 32 b x 2 pj). Wave: 128 o x 64 px -> 8x4 MFMA tiles.
__global__ __launch_bounds__(256, 2) void tconv_main(
    const unsigned short* __restrict__ xp,
    const unsigned short* __restrict__ wp,
    const float* __restrict__ bias,
    float* __restrict__ out)
{
    // W only: 4 buffers x 8320 sh = 33280 sh = 66560 B
    __shared__ __align__(16) unsigned short lds[33280];
    unsigned short* wsh0 = lds;

    const int tid  = threadIdx.x;
    const int lane = tid & 63;
    const int w    = tid >> 6;       // wave 0..3
    const int pjw  = w >> 1;
    const int half = w & 1;
    const int lg   = lane >> 4;      // sub = (du,dv)
    const int ln   = lane & 15;
    const int du   = lg >> 1, dv = lg & 1;

    const int bid = blockIdx.x;
    const int wg  = (bid & 7) * 64 + (bid >> 3);   // XCD swizzle (512 % 8 == 0)
    const int n   = wg >> 4;
    const int aq  = (wg >> 1) & 7;
    const int pi  = wg & 1;
    const int a0  = aq * 4;

    const unsigned short* xpb = xp + (size_t)n * XP_N + (a0 + pi) * XP_U;
    const unsigned short* wpb = wp + pi * WP_PI;

    // per-lane fragment offsets (static after unroll)
    int xoff[4];
    #pragma unroll
    for (int jj = 0; jj < 4; ++jj) {
        int rr = half * 2 + (jj >> 1) + du;
        int vv = (jj & 1) * 16 + ln + pjw + dv;
        xoff[jj] = rr * XP_U + vv * 8;
    }
    const int wfoff = (pjw * 4 + lg) * WROW + ln * 8;

    f32x4 acc[8][4];
    #pragma unroll
    for (int i = 0; i < 8; ++i)
        #pragma unroll
        for (int jj = 0; jj < 4; ++jj)
            acc[i][jj] = (f32x4){0.f, 0.f, 0.f, 0.f};

    short8 xA[4], xB[4];

#define STAGE_W(CH, WBUF)                                                    \
    { const unsigned short* ws_ = wpb + (size_t)(CH) * WP_G;                 \
      unsigned short* wd_ = wsh0 + (WBUF) * WBUFS;                           \
      _Pragma("unroll")                                                      \
      for (int s_ = 0; s_ < 4; ++s_) {                                       \
          int r_ = w * 2 + (s_ >> 1), h_ = s_ & 1;                           \
          ld_lds16(ws_ + r_ * 1024 + h_ * 512 + lane * 8,                    \
                   wd_ + r_ * WROW + h_ * 512); } }

#define LOAD_X(CH, XS)                                                      \
    { const unsigned short* xs_ = xpb + (size_t)(CH) * XP_G;                 \
      _Pragma("unroll")                                                      \
      for (int jj_ = 0; jj_ < 4; ++jj_)                                      \
          XS[jj_] = *(const short8*)(xs_ + xoff[jj_]); }

// Body: wait vmcnt(VMN); barrier; [issue W(CH+3)]; ds_read+MFMA; [issue x(CH+2)]
#define CHUNK(BUF, XS, CH, VMN, DO_W, DO_X)                                  \
    {                                                                        \
        __builtin_amdgcn_sched_barrier(0);                                   \
        asm volatile("s_waitcnt vmcnt(" #VMN ")" ::: "memory");              \
        __builtin_amdgcn_s_barrier();                                        \
        __builtin_amdgcn_sched_barrier(0);                                   \
        if (DO_W) STAGE_W((CH) + 3, ((BUF) + 3) & 3);                        \
        const unsigned short* wb_ = wsh0 + (BUF) * WBUFS + wfoff;            \
        _Pragma("unroll")                                                    \
        for (int i_ = 0; i_ < 8; ++i_) {                                     \
            short8 av_ = *(const short8*)&wb_[i_ * 128];                     \
            _Pragma("unroll")                                                \
            for (int jj_ = 0; jj_ < 4; ++jj_)                                \
                acc[i_][jj_] = __builtin_amdgcn_mfma_f32_16x16x32_bf16(      \
                    av_, XS[jj_], acc[i_][jj_], 0, 0, 0);                    \
        }                                                                    \
        if (DO_X) LOAD_X((CH) + 2, XS);                                      \
    }

    // Prologue — issue order defines the vmcnt ledger:
    // [W0, W1, x0, W2, x1] -> first wait vmcnt(8) retires W0,W1,x0.
    STAGE_W(0, 0);
    STAGE_W(1, 1);
    __builtin_amdgcn_sched_barrier(0);
    LOAD_X(0, xA);
    __builtin_amdgcn_sched_barrier(0);
    STAGE_W(2, 2);
    __builtin_amdgcn_sched_barrier(0);
    LOAD_X(1, xB);
    __builtin_amdgcn_sched_barrier(0);

    for (int ch4 = 0; ch4 < 28; ch4 += 4) {
        CHUNK(0, xA, ch4 + 0, 8, 1, 1);
        CHUNK(1, xB, ch4 + 1, 8, 1, 1);
        CHUNK(2, xA, ch4 + 2, 8, 1, 1);
        CHUNK(3, xB, ch4 + 3, 8, 1, 1);
    }
    // Tail: ch=28 issues W31+x30; ch=29 issues x31; ch=30/31 drain.
    CHUNK(0, xA, 28, 8, 1, 1);
    CHUNK(1, xB, 29, 8, 0, 1);
    CHUNK(2, xA, 30, 4, 0, 0);
    CHUNK(3, xB, 31, 0, 0, 0);

#undef CHUNK
#undef LOAD_X
#undef STAGE_W

    // Epilogue: LDS transpose -> coalesced float4 stores.
    // epi[o_l*4+r][ar*2+pj][33] f32 = 16896 B, overlays lds.
    float* epi = (float*)lds;
    #pragma unroll
    for (int i = 0; i < 8; ++i) {
        __syncthreads();
        f32x4 bv = *(const f32x4*)&bias[i * 16 + lg * 4];
        #pragma unroll
        for (int jj = 0; jj < 4; ++jj) {
            int ar = half * 2 + (jj >> 1);
            int b  = (jj & 1) * 16 + ln;
            #pragma unroll
            for (int r = 0; r < 4; ++r)
                epi[((lg * 4 + r) * 8 + ar * 2 + pjw) * 33 + b] = acc[i][jj][r] + bv[r];
        }
        __syncthreads();
        #pragma unroll
        for (int k = 0; k < 4; ++k) {
            int f   = tid + k * 256;     // [0,1024) float4-store ids
            int row = f >> 4;            // o_l*4 + ar
            int q   = f & 15;
            float4 v;
            v.x = epi[(row * 2 + 0) * 33 + q * 2 + 0];
            v.y = epi[(row * 2 + 1) * 33 + q * 2 + 0];
            v.z = epi[(row * 2 + 0) * 33 + q * 2 + 1];
            v.w = epi[(row * 2 + 1) * 33 + q * 2 + 1];
            int o     = i * 16 + (row >> 2);
            int i_out = 2 * (a0 + (row & 3)) + pi;
            *(float4*)&out[(((size_t)n * 128 + o) * 64 + i_out) * 64 + q * 4] = v;
        }
    }
}

// =================== fallback: round-2 kernel (proven) ===================
__global__ __launch_bounds__(256) void prepack_w(const float* __restrict__ W,
                                                 unsigned short* __restrict__ Wp) {
    int t = blockIdx.x * 256 + threadIdx.x;
    int o = t >> 8, c = t & 255;
    const float4* src = (const float4*)(W + (size_t)(o * 256 + c) * 16);
    float4 q0 = src[0], q1 = src[1], q2 = src[2], q3 = src[3];
    float rows[4][4] = {{q0.x,q0.y,q0.z,q0.w},{q1.x,q1.y,q1.z,q1.w},
                        {q2.x,q2.y,q2.z,q2.w},{q3.x,q3.y,q3.z,q3.w}};
    #pragma unroll
    for (int pi = 0; pi < 2; ++pi)
    #pragma unroll
    for (int pj = 0; pj < 2; ++pj)
    #pragma unroll
    for (int du = 0; du < 2; ++du)
    #pragma unroll
    for (int dv = 0; dv < 2; ++dv)
        Wp[((((pi*2+pj)*4 + du*2+dv)*128 + o)*256) + c] = f2bf(rows[pi+2*du][pj+2*dv]);
}

template<bool PRE>
__global__ __launch_bounds__(512, 2) void tconv_mfma(
    const float* __restrict__ x, const float* __restrict__ W,
    const unsigned short* __restrict__ Wp, const float* __restrict__ bias,
    float* __restrict__ out)
{
    __shared__ __align__(16) unsigned short xsh[2][9 * 34 * 8];
    __shared__ __align__(16) unsigned short wsh[2][2 * 4 * 128 * 8];

    const int tid = threadIdx.x;
    const int bid = blockIdx.x;
    const int pi  = bid & 1;
    const int aq  = (bid >> 1) & 3;
    const int n   = bid >> 3;
    const int a0  = aq * 8;
    const int u0  = a0 + pi - 1;

    const int l   = tid & 63;
    const int w   = tid >> 6;
    const int pjw = w >> 2;
    const int q   = w & 3;
    const int lg  = l >> 4;
    const int ln  = l & 15;

    const int sv = tid & 31;
    const int sg = tid >> 5;

    f32x4 acc[8][4];
    #pragma unroll
    for (int i = 0; i < 8; ++i)
        #pragma unroll
        for (int jj = 0; jj < 4; ++jj)
            acc[i][jj] = (f32x4){0.f, 0.f, 0.f, 0.f};

    float    xv[5];
    ushort4v wv[4];
    float4   wa[2], wb[2];

    auto stage_load = [&](int ch) {
        const int c0 = ch * 8;
        #pragma unroll
        for (int s = 0; s < 5; ++s) {
            int p = sg * 5 + s;
            if (p < 72) {
                int c = p & 7, rr = p >> 3;
                int u = u0 + rr;
                xv[s] = ((unsigned)u < 32u)
                      ? x[((n*256 + c0 + c)*32 + u)*32 + sv] : 0.f;
            }
        }
        if (PRE) {
            #pragma unroll
            for (int k = 0; k < 4; ++k) {
                int uu = tid + k * 512;
                int chalf = uu & 1, o = (uu >> 1) & 127;
                int sub = (uu >> 8) & 3, pjq = (uu >> 10) & 1;
                wv[k] = *(const ushort4v*)&Wp[(((pi*2 + pjq)*4 + sub)*128 + o)*256
                                              + c0 + chalf*4];
            }
        } else {
            #pragma unroll
            for (int k = 0; k < 2; ++k) {
                int pr = tid + k * 512;
                int o = pr >> 3, c = pr & 7;
                const float* base = W + ((o*256 + c0 + c) << 4) + pi*4;
                wa[k] = *(const float4*)base;
                wb[k] = *(const float4*)(base + 8);
            }
        }
    };

    auto stage_write = [&](int buf) {
        #pragma unroll
        for (int s = 0; s < 5; ++s) {
            int p = sg * 5 + s;
            if (p < 72) {
                int c = p & 7, rr = p >> 3;
                xsh[buf][(rr*34 + sv + 1)*8 + c] = f2bf(xv[s]);
            }
        }
        if (tid < 144) {
            int pr = tid >> 1;
            int rr = pr >> 3, c = pr & 7;
            int cw = (tid & 1) * 33;
            xsh[buf][(rr*34 + cw)*8 + c] = 0;
        }
        if (PRE) {
            #pragma unroll
            for (int k = 0; k < 4; ++k) {
                int uu = tid + k * 512;
                int chalf = uu & 1, o = (uu >> 1) & 127;
                int sub = (uu >> 8) & 3, pjq = (uu >> 10) & 1;
                *(ushort4v*)&wsh[buf][(((pjq*4 + sub)*128 + o)*8) + chalf*4] = wv[k];
            }
        } else {
            #pragma unroll
            for (int k = 0; k < 2; ++k) {
                int pr = tid + k * 512;
                int o = pr >> 3, c = pr & 7;
                float ra[4] = {wa[k].x, wa[k].y, wa[k].z, wa[k].w};
                float rb[4] = {wb[k].x, wb[k].y, wb[k].z, wb[k].w};
                #pragma unroll
                for (int pj2 = 0; pj2 < 2; ++pj2)
                #pragma unroll
                for (int duu = 0; duu < 2; ++duu)
                #pragma unroll
                for (int dvv = 0; dvv < 2; ++dvv) {
                    float val = duu ? rb[pj2 + 2*dvv] : ra[pj2 + 2*dvv];
                    wsh[buf][(((pj2*4 + duu*2 + dvv)*128 + o)*8) + c] = f2bf(val);
                }
            }
        }
    };

    stage_load(0);
    stage_write(0);
    __syncthreads();

    for (int ch = 0; ch < 32; ++ch) {
        const int cur = ch & 1;
        if (ch + 1 < 32) stage_load(ch + 1);

        short8 bfr[4];
        #pragma unroll
        for (int jj = 0; jj < 4; ++jj) {
            int arow = q*2 + (jj >> 1);
            int b    = (jj & 1)*16 + ln;
            int rr   = arow + (lg >> 1);
            int cw   = b + pjw + (lg & 1);
            bfr[jj]  = *(const short8*)&xsh[cur][(rr*34 + cw)*8];
        }
        #pragma unroll
        for (int i = 0; i < 8; ++i) {
            short8 av = *(const short8*)&wsh[cur][((pjw*4 + lg)*128 + i*16 + ln)*8];
            #pragma unroll
            for (int jj = 0; jj < 4; ++jj)
                acc[i][jj] = __builtin_amdgcn_mfma_f32_16x16x32_bf16(
                                 av, bfr[jj], acc[i][jj], 0, 0, 0);
        }

        if (ch + 1 < 32) stage_write(cur ^ 1);
        __syncthreads();
    }

    #pragma unroll
    for (int i = 0; i < 8; ++i) {
        const f32x4 bv = *(const f32x4*)&bias[i*16 + lg*4];
        #pragma unroll
        for (int jj = 0; jj < 4; ++jj) {
            int arow  = q*2 + (jj >> 1);
            int b     = (jj & 1)*16 + ln;
            int i_out = 2*(a0 + arow) + pi;
            int j_out = 2*b + pjw;
            int o0    = i*16 + lg*4;
            int base  = ((n*128 + o0)*64 + i_out)*64 + j_out;
            #pragma unroll
            for (int r = 0; r < 4; ++r)
                out[base + r*4096] = acc[i][jj][r] + bv[r];
        }
    }
}

extern "C" void kernel_launch(void* const* d_in, const int* in_sizes, int n_in,
                              void* d_out, int out_size, void* d_ws, size_t ws_size,
                              hipStream_t stream) {
    const float* x    = (const float*)d_in[0];
    const float* W    = (const float*)d_in[1];
    const float* bias = (const float*)d_in[2];
    float* out        = (float*)d_out;

    const size_t wp2_bytes = (size_t)2 * WP_PI * 2;          // 1 MB
    const size_t xp_bytes  = (size_t)32 * XP_N * 2;          // ~20 MB
    if (ws_size >= wp2_bytes + xp_bytes) {
        unsigned short* wp2 = (unsigned short*)d_ws;
        unsigned short* xpp = (unsigned short*)((char*)d_ws + wp2_bytes);
        prepack_w2<<<128, 256, 0, stream>>>(W, wp2);
        prepack_x<<<dim3(34, 32), 256, 0, stream>>>(x, xpp);
        tconv_main<<<512, 256, 0, stream>>>(xpp, wp2, bias, out);
    } else if (ws_size >= (size_t)4*4*128*256*2) {
        unsigned short* Wp = (unsigned short*)d_ws;
        prepack_w<<<128, 256, 0, stream>>>(W, Wp);
        tconv_mfma<true><<<256, 512, 0, stream>>>(x, W, Wp, bias, out);
    } else {
        tconv_mfma<false><<<256, 512, 0, stream>>>(x, W, nullptr, bias, out);
    }
}